// Round 8
// baseline (235.040 us; speedup 1.0000x reference)
//
#include <hip/hip_runtime.h>
#include <hip/hip_bf16.h>

#define LLEN 512
#define SLEN 64
#define EMBD 16
#define EE 48
#define GG 4
#define NHH 8
#define KDD 4
#define INDIM 224
#define H1D 200
#define H2D 80
#define CHUNK 128
#define PXE 52   // long-term row stride: 48 data + 4 selector floats
#define TXS 65   // transposed attention stride (odd -> conflict-free both ways)

__device__ __forceinline__ float bf2f(unsigned short u) {
    union { unsigned int i; float f; } v; v.i = ((unsigned int)u) << 16; return v.f;
}

template<bool BF16>
__device__ __forceinline__ float ldf(const void* p, int i) {
    if constexpr (BF16) return bf2f(((const unsigned short*)p)[i]);
    else                return ((const float*)p)[i];
}

template<bool BF16>
__device__ __forceinline__ float4 ld4(const void* p, int i4) {
    if constexpr (BF16) {
        ushort4 u = ((const ushort4*)p)[i4 >> 2];
        return make_float4(bf2f(u.x), bf2f(u.y), bf2f(u.z), bf2f(u.w));
    } else {
        return ((const float4*)p)[i4 >> 2];
    }
}

// H source resolved at COMPILE time per kernel instantiation (no runtime ternary
// in the hot loop — R7's `hf ? : ` materialized both arms = 2x VALU).
template<bool BF16, bool HWS>
__device__ __forceinline__ float hload(const float* hf, const void* Hm, int i) {
    if constexpr (HWS) return hf[i];            // fp32 workspace, uniform idx -> s_load
    else               return ldf<BF16>(Hm, i); // fallback only (ws missing)
}

// ---- prep: dtype detect + H -> fp32 workspace (bf16 evens are small values;
// fp32 evens are random mantissa bits: P[all 128 exp<127] ~ 2^-128).
__global__ void prep_kernel(const unsigned short* __restrict__ tbl,
                            const void* __restrict__ Hm, float* __restrict__ hf) {
    int t = threadIdx.x;   // 64
    int big = 0;
    for (int i = t; i < 128; i += 64) {
        unsigned short u = tbl[2 * i];
        if (((u >> 7) & 0xFF) >= 127) big = 1;
    }
    unsigned long long m = __ballot(big);
    int isbf = (m == 0ull) ? 1 : 0;
    for (int i = t; i < EE * 12; i += 64)
        hf[i] = isbf ? bf2f(((const unsigned short*)Hm)[i]) : ((const float*)Hm)[i];
}

struct Pool {
    float buf[CHUNK * PXE + 16];   // chunk rows / attention (XsT etc) / MLP scratch
    float part[GG][GG][EE];        // [wid][g][e] selected-bucket partial sums
    float feat[INDIM];
    float q[NHH * KDD];
    float red[128];
    int   pc[2][GG];               // counts from waves 0,2
    int   icode[GG];
    int   len;
    float mu, rstd;
};

template<bool BF16, bool HWS>
__device__ void sdim_body(Pool& P,
    const int* uid, const int* ut1, const int* ut2, const int* ut3, const int* ut4,
    const int* lb_g, const int* lb_s, const int* lb_c,
    const int* lt_g, const int* lt_s, const int* lt_c,
    const int* st_g, const int* st_s, const int* st_c,
    const void* tbl, const void* Hm,
    const void* wq, const void* bq, const void* wk, const void* bk,
    const void* wvv, const void* bv, const void* wo, const void* bo,
    const void* w1, const void* b1, const void* g1, const void* be1,
    const void* w2, const void* b2, const void* g2, const void* be2,
    const void* w3, const void* b3, void* outp, const float* hf)
{
    const int b = blockIdx.x;
    const int tid = threadIdx.x;
    const int lane = tid & 63;
    const int wid = __builtin_amdgcn_readfirstlane(tid >> 6);   // 0..3 uniform

    // ---------------- phase 0: Xu/Xi embeds -> feat ----------------
    if (tid < 80) {
        int f = tid >> 4, e = tid & 15;
        int id = (f == 0) ? uid[b] : (f == 1) ? ut1[b] : (f == 2) ? ut2[b] : (f == 3) ? ut3[b] : ut4[b];
        P.feat[tid] = ldf<BF16>(tbl, id * EMBD + e);
    } else if (tid < 128) {
        int t = tid - 80; int f = t >> 4, e = t & 15;
        int id = (f == 0) ? lb_g[b] : (f == 1) ? lb_s[b] : lb_c[b];
        P.feat[80 + t] = ldf<BF16>(tbl, id * EMBD + e);
    }
    __syncthreads();

    // ---------------- phase 0.5: q projection + item LSH codes ----------------
    if (tid < 32) {
        float acc = ldf<BF16>(bq, tid);
        for (int e = 0; e < EE; e++) acc += P.feat[80 + e] * ldf<BF16>(wq, e * 32 + tid);
        P.q[tid] = acc;
    }
    if (tid >= 64 && tid < 76) {
        int j = tid - 64;
        float acc = 0.f;
        for (int e = 0; e < EE; e++) acc += P.feat[80 + e] * hload<BF16, HWS>(hf, Hm, e * 12 + j);
        P.red[j] = acc;
    }
    __syncthreads();
    if (tid < GG) {
        int code = 0;
        #pragma unroll
        for (int m = 0; m < 3; m++) if (P.red[tid * 3 + m] > 0.f) code |= (1 << m);
        P.icode[tid] = code;
    }

    // ---------------- phase 1: long-term, 4 chunks of 128 positions ----------------
    float accg[GG] = {0.f, 0.f, 0.f, 0.f};     // lane = e, selected-bucket sums
    int   cnt[GG]  = {0, 0, 0, 0};             // wave-uniform counts (waves 0,2)
    const int offs = (lane < 52) ? lane : 51;

    for (int ch = 0; ch < LLEN / CHUNK; ch++) {
        const int base = ch * CHUNK;
        // A: pipelined gather
        {
            int ids[6];
            #pragma unroll
            for (int i = 0; i < 6; i++) {
                int f = tid + 256 * i;
                int p = f / 12, qq = f - 12 * p, fe = qq >> 2;
                const int* idp = (fe == 0) ? lt_g : (fe == 1) ? lt_s : lt_c;
                ids[i] = idp[b * LLEN + base + p];
            }
            float4 vs[6];
            #pragma unroll
            for (int i = 0; i < 6; i++) {
                int f = tid + 256 * i;
                int p = f / 12, qq = f - 12 * p;
                vs[i] = ld4<BF16>(tbl, ids[i] * EMBD + ((qq & 3) << 2));
            }
            #pragma unroll
            for (int i = 0; i < 6; i++) {
                int f = tid + 256 * i;
                int p = f / 12, qq = f - 12 * p;
                *(float4*)&P.buf[p * PXE + (qq << 2)] = vs[i];
            }
        }
        __syncthreads();
        // B: LSH codes + selectors, one thread per position (waves 0,2).
        // k-outer/j-inner: ~20 live VGPRs; H via s_load SGPR operands (HWS path).
        if (!(wid & 1)) {
            const int p = ((wid >> 1) << 6) | lane;
            const float* row = &P.buf[p * PXE];
            float acc[12];
            #pragma unroll
            for (int j = 0; j < 12; j++) acc[j] = 0.f;
            #pragma unroll
            for (int k = 0; k < 12; k++) {
                float4 x4 = *(const float4*)(row + 4 * k);
                #pragma unroll
                for (int j = 0; j < 12; j++) {
                    acc[j] += x4.x * hload<BF16, HWS>(hf, Hm, (4 * k + 0) * 12 + j)
                            + x4.y * hload<BF16, HWS>(hf, Hm, (4 * k + 1) * 12 + j)
                            + x4.z * hload<BF16, HWS>(hf, Hm, (4 * k + 2) * 12 + j)
                            + x4.w * hload<BF16, HWS>(hf, Hm, (4 * k + 3) * 12 + j);
                }
            }
            int code[GG];
            #pragma unroll
            for (int g = 0; g < GG; g++) {
                int c = 0;
                #pragma unroll
                for (int m = 0; m < 3; m++) if (acc[g * 3 + m] > 0.f) c |= (1 << m);
                code[g] = c;
            }
            int valid = (lt_g[b * LLEN + base + p] != 0);
            float4 sel;
            sel.x = (code[0] == P.icode[0] && valid) ? 1.f : 0.f;
            sel.y = (code[1] == P.icode[1] && valid) ? 1.f : 0.f;
            sel.z = (code[2] == P.icode[2] && valid) ? 1.f : 0.f;
            sel.w = (code[3] == P.icode[3] && valid) ? 1.f : 0.f;
            *(float4*)&P.buf[p * PXE + 48] = sel;
            #pragma unroll
            for (int g = 0; g < GG; g++)   // counts include padded positions (ref semantics)
                cnt[g] += __popcll(__ballot(code[g] == P.icode[g]));
        }
        __syncthreads();
        // C: branch-free selected-bucket accumulation; one ds_read gets row data
        // (lanes 0..47) + selectors (lanes 48..51); readlane broadcasts sel.
        {
            const float* basep = &P.buf[(wid * 32) * PXE] + offs;
            #pragma unroll
            for (int i = 0; i < 32; i++) {
                float xv = basep[i * PXE];
                #pragma unroll
                for (int g = 0; g < GG; g++) {
                    float sel = __int_as_float(
                        __builtin_amdgcn_readlane(__float_as_int(xv), 48 + g));
                    accg[g] += sel * xv;
                }
            }
        }
        __syncthreads();
    }
    if (lane < EE) {
        #pragma unroll
        for (int g = 0; g < GG; g++) P.part[wid][g][lane] = accg[g];
    }
    if (!(wid & 1) && lane == 0) {
        #pragma unroll
        for (int g = 0; g < GG; g++) P.pc[wid >> 1][g] = cnt[g];
    }
    __syncthreads();

    // ---------------- phase 2: long-term interest -> feat[128:176] ----------------
    if (tid < EE) {
        float r = 0.f;
        #pragma unroll
        for (int g = 0; g < GG; g++) {
            float c = (float)(P.pc[0][g] + P.pc[1][g]);
            float s = P.part[0][g][tid] + P.part[1][g][tid] + P.part[2][g][tid] + P.part[3][g][tid];
            r += s / fmaxf(c, 1.0f);
        }
        P.feat[128 + tid] = r * 0.25f;
    }

    // ---------------- phase 3: short-term attention (transposed Xs) ----------------
    float* XsT  = P.buf;                  // [48][TXS]
    float* wkq  = P.buf + EE * TXS;       // [48][8]
    float* bkq  = wkq + EE * NHH;         // [8]
    float* sc   = bkq + NHH;              // [8][64]
    float* su   = sc + NHH * SLEN;        // [8][48]
    float* sctx = su + NHH * EE;          // [32]

    {
        int ids[3];
        #pragma unroll
        for (int i = 0; i < 3; i++) {
            int f = tid + 256 * i;
            int p = f / 12, qq = f - 12 * p, fe = qq >> 2;
            const int* idp = (fe == 0) ? st_g : (fe == 1) ? st_s : st_c;
            ids[i] = idp[b * SLEN + p];
        }
        float4 vs[3];
        #pragma unroll
        for (int i = 0; i < 3; i++) {
            int f = tid + 256 * i;
            int p = f / 12, qq = f - 12 * p;
            vs[i] = ld4<BF16>(tbl, ids[i] * EMBD + ((qq & 3) << 2));
        }
        #pragma unroll
        for (int i = 0; i < 3; i++) {
            int f = tid + 256 * i;
            int p = f / 12, qq = f - 12 * p;   // e_base = 4*qq, s = p
            XsT[(4 * qq + 0) * TXS + p] = vs[i].x;
            XsT[(4 * qq + 1) * TXS + p] = vs[i].y;
            XsT[(4 * qq + 2) * TXS + p] = vs[i].z;
            XsT[(4 * qq + 3) * TXS + p] = vs[i].w;
        }
    }
    if (tid < 64) {
        unsigned long long msk = __ballot(st_g[b * SLEN + tid] != 0);
        if (tid == 0) P.len = __popcll(msk);
    }
    for (int t = tid; t < EE * NHH; t += 256) {
        int e = t >> 3, h = t & 7;
        float acc = 0.f;
        #pragma unroll
        for (int d = 0; d < KDD; d++) acc += ldf<BF16>(wk, e * 32 + h * 4 + d) * P.q[h * 4 + d];
        wkq[t] = acc;
    }
    if (tid < NHH) {
        float acc = 0.f;
        #pragma unroll
        for (int d = 0; d < KDD; d++) acc += ldf<BF16>(bk, tid * 4 + d) * P.q[tid * 4 + d];
        bkq[tid] = acc;
    }
    __syncthreads();
    for (int t = tid; t < NHH * SLEN; t += 256) {
        int h = t >> 6, s = t & 63;          // lanes vary s: XsT stride-1 reads
        float acc = bkq[h];
        for (int e = 0; e < EE; e++) acc += XsT[e * TXS + s] * wkq[e * NHH + h];
        acc *= 0.5f;
        if (s >= P.len) acc -= 1e9f;
        sc[h * SLEN + s] = acc;
    }
    __syncthreads();
    for (int h = wid; h < NHH; h += 4) {
        float v = sc[h * SLEN + lane];
        float mx = v;
        #pragma unroll
        for (int o = 32; o; o >>= 1) mx = fmaxf(mx, __shfl_xor(mx, o));
        float ex = __expf(v - mx);
        float sm = ex;
        #pragma unroll
        for (int o = 32; o; o >>= 1) sm += __shfl_xor(sm, o);
        sc[h * SLEN + lane] = ex / sm;
    }
    __syncthreads();
    for (int t = tid; t < NHH * EE; t += 256) {
        int h = t / EE, e = t - h * EE;      // lanes vary e: XsT stride-65 (odd) reads
        float acc = 0.f;
        for (int s = 0; s < SLEN; s++) acc += sc[h * SLEN + s] * XsT[e * TXS + s];
        su[t] = acc;
    }
    __syncthreads();
    if (tid < 32) {
        float acc = ldf<BF16>(bv, tid);
        int h = tid >> 2;
        for (int e = 0; e < EE; e++) acc += su[h * EE + e] * ldf<BF16>(wvv, e * 32 + tid);
        sctx[tid] = acc;
    }
    __syncthreads();
    if (tid < EE) {
        float acc = ldf<BF16>(bo, tid);
        #pragma unroll
        for (int i = 0; i < 32; i++) acc += sctx[i] * ldf<BF16>(wo, i * EE + tid);
        P.feat[176 + tid] = acc;
    }
    __syncthreads();

    // ---------------- phase 4: MLP ----------------
    float z1 = 0.f;
    if (tid < H1D) {
        z1 = ldf<BF16>(b1, tid);
        for (int i = 0; i < INDIM; i++) z1 += P.feat[i] * ldf<BF16>(w1, i * H1D + tid);
        P.buf[tid] = z1;
    }
    __syncthreads();
    if (tid < 64) {
        float sm = 0.f, sq = 0.f;
        for (int j = tid; j < H1D; j += 64) { float v = P.buf[j]; sm += v; sq += v * v; }
        #pragma unroll
        for (int o = 32; o; o >>= 1) { sm += __shfl_xor(sm, o); sq += __shfl_xor(sq, o); }
        if (tid == 0) { float mu = sm / H1D; P.mu = mu; P.rstd = rsqrtf(sq / H1D - mu * mu + 1e-3f); }
    }
    __syncthreads();
    if (tid < H1D) {
        float h = fmaxf(ldf<BF16>(g1, tid) * (z1 - P.mu) * P.rstd + ldf<BF16>(be1, tid), 0.f);
        P.buf[256 + tid] = h;
    }
    __syncthreads();
    float z2 = 0.f;
    if (tid < H2D) {
        z2 = ldf<BF16>(b2, tid);
        for (int i = 0; i < H1D; i++) z2 += P.buf[256 + i] * ldf<BF16>(w2, i * H2D + tid);
        P.buf[tid] = z2;
    }
    __syncthreads();
    if (tid < 64) {
        float sm = 0.f, sq = 0.f;
        for (int j = tid; j < H2D; j += 64) { float v = P.buf[j]; sm += v; sq += v * v; }
        #pragma unroll
        for (int o = 32; o; o >>= 1) { sm += __shfl_xor(sm, o); sq += __shfl_xor(sq, o); }
        if (tid == 0) { float mu = sm / H2D; P.mu = mu; P.rstd = rsqrtf(sq / H2D - mu * mu + 1e-3f); }
    }
    __syncthreads();
    if (tid < H2D) {
        float h = fmaxf(ldf<BF16>(g2, tid) * (z2 - P.mu) * P.rstd + ldf<BF16>(be2, tid), 0.f);
        P.red[tid] = h * ldf<BF16>(w3, tid);
    }
    __syncthreads();
    if (tid == 0) {
        float acc = ldf<BF16>(b3, 0);
        for (int i = 0; i < H2D; i++) acc += P.red[i];
        float sig = 1.f / (1.f + __expf(-acc));
        if constexpr (BF16) ((__hip_bfloat16*)outp)[b] = __float2bfloat16(sig);
        else                ((float*)outp)[b] = sig;
    }
}

template<bool HWS>
__global__ __launch_bounds__(256, 4) void sdim_fwd(
    const int* __restrict__ uid, const int* __restrict__ ut1, const int* __restrict__ ut2,
    const int* __restrict__ ut3, const int* __restrict__ ut4,
    const int* __restrict__ lb_g, const int* __restrict__ lb_s, const int* __restrict__ lb_c,
    const int* __restrict__ lt_g, const int* __restrict__ lt_s, const int* __restrict__ lt_c,
    const int* __restrict__ st_g, const int* __restrict__ st_s, const int* __restrict__ st_c,
    const void* __restrict__ tbl, const void* __restrict__ Hm,
    const void* __restrict__ wq, const void* __restrict__ bq,
    const void* __restrict__ wk, const void* __restrict__ bk,
    const void* __restrict__ wvv, const void* __restrict__ bv,
    const void* __restrict__ wo, const void* __restrict__ bo,
    const void* __restrict__ w1, const void* __restrict__ b1,
    const void* __restrict__ g1, const void* __restrict__ be1,
    const void* __restrict__ w2, const void* __restrict__ b2,
    const void* __restrict__ g2, const void* __restrict__ be2,
    const void* __restrict__ w3, const void* __restrict__ b3,
    void* __restrict__ outp, const float* __restrict__ hf)
{
    __shared__ Pool P;
    __shared__ int s_isbf;
    if (threadIdx.x < 64) {
        int big = 0;
        for (int i = (threadIdx.x & 63); i < 128; i += 64) {
            unsigned short u = ((const unsigned short*)tbl)[2 * i];
            if (((u >> 7) & 0xFF) >= 127) big = 1;
        }
        unsigned long long m = __ballot(big);
        if (threadIdx.x == 0) s_isbf = (m == 0ull) ? 1 : 0;
    }
    __syncthreads();
    if (s_isbf)
        sdim_body<true , HWS>(P, uid, ut1, ut2, ut3, ut4, lb_g, lb_s, lb_c, lt_g, lt_s, lt_c,
                              st_g, st_s, st_c, tbl, Hm, wq, bq, wk, bk, wvv, bv, wo, bo,
                              w1, b1, g1, be1, w2, b2, g2, be2, w3, b3, outp, hf);
    else
        sdim_body<false, HWS>(P, uid, ut1, ut2, ut3, ut4, lb_g, lb_s, lb_c, lt_g, lt_s, lt_c,
                              st_g, st_s, st_c, tbl, Hm, wq, bq, wk, bk, wvv, bv, wo, bo,
                              w1, b1, g1, be1, w2, b2, g2, be2, w3, b3, outp, hf);
}

extern "C" void kernel_launch(void* const* d_in, const int* in_sizes, int n_in,
                              void* d_out, int out_size, void* d_ws, size_t ws_size,
                              hipStream_t stream) {
    const int B = in_sizes[0];   // batch = 1024
    const bool has_ws = ws_size >= (16 + EE * 12) * sizeof(float);
    float* hf = has_ws ? ((float*)d_ws + 16) : nullptr;
    if (has_ws)
        prep_kernel<<<1, 64, 0, stream>>>((const unsigned short*)d_in[14], d_in[15], hf);

#define ARGS \
        (const int*)d_in[0],  (const int*)d_in[1],  (const int*)d_in[2],              \
        (const int*)d_in[3],  (const int*)d_in[4],                                    \
        (const int*)d_in[5],  (const int*)d_in[6],  (const int*)d_in[7],              \
        (const int*)d_in[8],  (const int*)d_in[9],  (const int*)d_in[10],             \
        (const int*)d_in[11], (const int*)d_in[12], (const int*)d_in[13],             \
        (const void*)d_in[14], (const void*)d_in[15],                                 \
        (const void*)d_in[16], (const void*)d_in[17],                                 \
        (const void*)d_in[18], (const void*)d_in[19],                                 \
        (const void*)d_in[20], (const void*)d_in[21],                                 \
        (const void*)d_in[22], (const void*)d_in[23],                                 \
        (const void*)d_in[24], (const void*)d_in[25],                                 \
        (const void*)d_in[26], (const void*)d_in[27],                                 \
        (const void*)d_in[28], (const void*)d_in[29],                                 \
        (const void*)d_in[30], (const void*)d_in[31],                                 \
        (const void*)d_in[32], (const void*)d_in[33],                                 \
        d_out, hf

    if (has_ws) sdim_fwd<true ><<<B, 256, 0, stream>>>(ARGS);
    else        sdim_fwd<false><<<B, 256, 0, stream>>>(ARGS);
#undef ARGS
}

// Round 9
// 221.804 us; speedup vs baseline: 1.0597x; 1.0597x over previous
//
#include <hip/hip_runtime.h>
#include <hip/hip_bf16.h>

#define LLEN 512
#define SLEN 64
#define EMBD 16
#define EE 48
#define GG 4
#define NHH 8
#define KDD 4
#define INDIM 224
#define H1D 200
#define H2D 80
#define CHUNK 128
#define PXE 52   // long-term row stride: 48 data + 4 selector floats
#define TXS 65   // transposed attention stride (odd -> conflict-free both ways)

__device__ __forceinline__ float bf2f(unsigned short u) {
    union { unsigned int i; float f; } v; v.i = ((unsigned int)u) << 16; return v.f;
}

template<bool BF16>
__device__ __forceinline__ float ldf(const void* p, int i) {
    if constexpr (BF16) return bf2f(((const unsigned short*)p)[i]);
    else                return ((const float*)p)[i];
}

template<bool BF16>
__device__ __forceinline__ float4 ld4(const void* p, int i4) {
    if constexpr (BF16) {
        ushort4 u = ((const ushort4*)p)[i4 >> 2];
        return make_float4(bf2f(u.x), bf2f(u.y), bf2f(u.z), bf2f(u.w));
    } else {
        return ((const float4*)p)[i4 >> 2];
    }
}

struct Pool {
    float buf[CHUNK * PXE + 16];   // chunk rows / attention (XsT etc) / MLP scratch
    // hl (H transposed fp32, [j][e]) is dead before part is first written -> union
    union alignas(16) {
        float hl[12 * EE];         // hl[j*48+e] = H[e][j]
        float part[GG][GG][EE];    // [wid][g][e] selected-bucket partial sums
    } u;
    float feat[INDIM];
    float q[NHH * KDD];
    float red[128];
    int   pc[2][GG];               // counts from waves 0,2
    int   icode[GG];
    int   len;
    float mu, rstd;
};

template<bool BF16>
__device__ void sdim_body(Pool& P,
    const int* uid, const int* ut1, const int* ut2, const int* ut3, const int* ut4,
    const int* lb_g, const int* lb_s, const int* lb_c,
    const int* lt_g, const int* lt_s, const int* lt_c,
    const int* st_g, const int* st_s, const int* st_c,
    const void* tbl, const void* Hm,
    const void* wq, const void* bq, const void* wk, const void* bk,
    const void* wvv, const void* bv, const void* wo, const void* bo,
    const void* w1, const void* b1, const void* g1, const void* be1,
    const void* w2, const void* b2, const void* g2, const void* be2,
    const void* w3, const void* b3, void* outp)
{
    const int b = blockIdx.x;
    const int tid = threadIdx.x;
    const int lane = tid & 63;
    const int wid = __builtin_amdgcn_readfirstlane(tid >> 6);   // 0..3 uniform

    // ---------------- phase 0: H -> LDS fp32 transposed; Xu/Xi embeds ----------------
    for (int i = tid; i < 12 * EE; i += 256) {
        int j = i / EE, e = i - j * EE;
        P.u.hl[i] = ldf<BF16>(Hm, e * 12 + j);
    }
    if (tid < 80) {
        int f = tid >> 4, e = tid & 15;
        int id = (f == 0) ? uid[b] : (f == 1) ? ut1[b] : (f == 2) ? ut2[b] : (f == 3) ? ut3[b] : ut4[b];
        P.feat[tid] = ldf<BF16>(tbl, id * EMBD + e);
    } else if (tid < 128) {
        int t = tid - 80; int f = t >> 4, e = t & 15;
        int id = (f == 0) ? lb_g[b] : (f == 1) ? lb_s[b] : lb_c[b];
        P.feat[80 + t] = ldf<BF16>(tbl, id * EMBD + e);
    }
    __syncthreads();

    // ---------------- phase 0.5: q projection + item LSH codes ----------------
    if (tid < 32) {
        float acc = ldf<BF16>(bq, tid);
        for (int e = 0; e < EE; e++) acc += P.feat[80 + e] * ldf<BF16>(wq, e * 32 + tid);
        P.q[tid] = acc;
    }
    if (tid >= 64 && tid < 76) {
        int j = tid - 64;
        float acc = 0.f;
        for (int e = 0; e < EE; e++) acc += P.feat[80 + e] * P.u.hl[j * EE + e];
        P.red[j] = acc;
    }
    __syncthreads();
    if (tid < GG) {
        int code = 0;
        #pragma unroll
        for (int m = 0; m < 3; m++) if (P.red[tid * 3 + m] > 0.f) code |= (1 << m);
        P.icode[tid] = code;
    }

    // ---------------- phase 1: long-term, 4 chunks of 128 positions ----------------
    float accg[GG] = {0.f, 0.f, 0.f, 0.f};     // lane = e, selected-bucket sums
    int   cnt[GG]  = {0, 0, 0, 0};             // wave-uniform counts (waves 0,2)
    const int offs = (lane < 52) ? lane : 51;

    for (int ch = 0; ch < LLEN / CHUNK; ch++) {
        const int base = ch * CHUNK;
        // A: pipelined gather
        {
            int ids[6];
            #pragma unroll
            for (int i = 0; i < 6; i++) {
                int f = tid + 256 * i;
                int p = f / 12, qq = f - 12 * p, fe = qq >> 2;
                const int* idp = (fe == 0) ? lt_g : (fe == 1) ? lt_s : lt_c;
                ids[i] = idp[b * LLEN + base + p];
            }
            float4 vs[6];
            #pragma unroll
            for (int i = 0; i < 6; i++) {
                int f = tid + 256 * i;
                int p = f / 12, qq = f - 12 * p;
                vs[i] = ld4<BF16>(tbl, ids[i] * EMBD + ((qq & 3) << 2));
            }
            #pragma unroll
            for (int i = 0; i < 6; i++) {
                int f = tid + 256 * i;
                int p = f / 12, qq = f - 12 * p;
                *(float4*)&P.buf[p * PXE + (qq << 2)] = vs[i];
            }
        }
        __syncthreads();
        // B: LSH codes + selectors, one thread per position (waves 0,2).
        // j-outer, x[12] VGPR-resident, H float4s from LDS (broadcast, conflict-free).
        // launch_bounds(256,2) gives VGPR headroom so x[12] does NOT spill (R6's bug).
        if (!(wid & 1)) {
            const int p = ((wid >> 1) << 6) | lane;
            const float* row = &P.buf[p * PXE];
            float4 x[12];
            #pragma unroll
            for (int k = 0; k < 12; k++) x[k] = *(const float4*)(row + 4 * k);
            float acc[12];
            #pragma unroll
            for (int j = 0; j < 12; j++) {
                const float4* hr = (const float4*)&P.u.hl[j * EE];
                float s = 0.f;
                #pragma unroll
                for (int k = 0; k < 12; k++) {
                    float4 h4 = hr[k];
                    s += x[k].x * h4.x + x[k].y * h4.y + x[k].z * h4.z + x[k].w * h4.w;
                }
                acc[j] = s;
            }
            int code[GG];
            #pragma unroll
            for (int g = 0; g < GG; g++) {
                int c = 0;
                #pragma unroll
                for (int m = 0; m < 3; m++) if (acc[g * 3 + m] > 0.f) c |= (1 << m);
                code[g] = c;
            }
            int valid = (lt_g[b * LLEN + base + p] != 0);
            float4 sel;
            sel.x = (code[0] == P.icode[0] && valid) ? 1.f : 0.f;
            sel.y = (code[1] == P.icode[1] && valid) ? 1.f : 0.f;
            sel.z = (code[2] == P.icode[2] && valid) ? 1.f : 0.f;
            sel.w = (code[3] == P.icode[3] && valid) ? 1.f : 0.f;
            *(float4*)&P.buf[p * PXE + 48] = sel;
            #pragma unroll
            for (int g = 0; g < GG; g++)   // counts include padded positions (ref semantics)
                cnt[g] += __popcll(__ballot(code[g] == P.icode[g]));
        }
        __syncthreads();
        // C: branch-free selected-bucket accumulation; one ds_read gets row data
        // (lanes 0..47) + selectors (lanes 48..51); readlane broadcasts sel.
        {
            const float* basep = &P.buf[(wid * 32) * PXE] + offs;
            #pragma unroll
            for (int i = 0; i < 32; i++) {
                float xv = basep[i * PXE];
                #pragma unroll
                for (int g = 0; g < GG; g++) {
                    float sel = __int_as_float(
                        __builtin_amdgcn_readlane(__float_as_int(xv), 48 + g));
                    accg[g] += sel * xv;
                }
            }
        }
        __syncthreads();
    }
    // flush (hl is dead now; union member part takes over)
    if (lane < EE) {
        #pragma unroll
        for (int g = 0; g < GG; g++) P.u.part[wid][g][lane] = accg[g];
    }
    if (!(wid & 1) && lane == 0) {
        #pragma unroll
        for (int g = 0; g < GG; g++) P.pc[wid >> 1][g] = cnt[g];
    }
    __syncthreads();

    // ---------------- phase 2: long-term interest -> feat[128:176] ----------------
    if (tid < EE) {
        float r = 0.f;
        #pragma unroll
        for (int g = 0; g < GG; g++) {
            float c = (float)(P.pc[0][g] + P.pc[1][g]);
            float s = P.u.part[0][g][tid] + P.u.part[1][g][tid]
                    + P.u.part[2][g][tid] + P.u.part[3][g][tid];
            r += s / fmaxf(c, 1.0f);
        }
        P.feat[128 + tid] = r * 0.25f;
    }

    // ---------------- phase 3: short-term attention (transposed Xs) ----------------
    float* XsT  = P.buf;                  // [48][TXS]
    float* wkq  = P.buf + EE * TXS;       // [48][8]
    float* bkq  = wkq + EE * NHH;         // [8]
    float* sc   = bkq + NHH;              // [8][64]
    float* su   = sc + NHH * SLEN;        // [8][48]
    float* sctx = su + NHH * EE;          // [32]

    {
        int ids[3];
        #pragma unroll
        for (int i = 0; i < 3; i++) {
            int f = tid + 256 * i;
            int p = f / 12, qq = f - 12 * p, fe = qq >> 2;
            const int* idp = (fe == 0) ? st_g : (fe == 1) ? st_s : st_c;
            ids[i] = idp[b * SLEN + p];
        }
        float4 vs[3];
        #pragma unroll
        for (int i = 0; i < 3; i++) {
            int f = tid + 256 * i;
            int p = f / 12, qq = f - 12 * p;
            vs[i] = ld4<BF16>(tbl, ids[i] * EMBD + ((qq & 3) << 2));
        }
        #pragma unroll
        for (int i = 0; i < 3; i++) {
            int f = tid + 256 * i;
            int p = f / 12, qq = f - 12 * p;   // e_base = 4*qq, s = p
            XsT[(4 * qq + 0) * TXS + p] = vs[i].x;
            XsT[(4 * qq + 1) * TXS + p] = vs[i].y;
            XsT[(4 * qq + 2) * TXS + p] = vs[i].z;
            XsT[(4 * qq + 3) * TXS + p] = vs[i].w;
        }
    }
    if (tid < 64) {
        unsigned long long msk = __ballot(st_g[b * SLEN + tid] != 0);
        if (tid == 0) P.len = __popcll(msk);
    }
    for (int t = tid; t < EE * NHH; t += 256) {
        int e = t >> 3, h = t & 7;
        float acc = 0.f;
        #pragma unroll
        for (int d = 0; d < KDD; d++) acc += ldf<BF16>(wk, e * 32 + h * 4 + d) * P.q[h * 4 + d];
        wkq[t] = acc;
    }
    if (tid < NHH) {
        float acc = 0.f;
        #pragma unroll
        for (int d = 0; d < KDD; d++) acc += ldf<BF16>(bk, tid * 4 + d) * P.q[tid * 4 + d];
        bkq[tid] = acc;
    }
    __syncthreads();
    for (int t = tid; t < NHH * SLEN; t += 256) {
        int h = t >> 6, s = t & 63;          // lanes vary s: XsT stride-1 reads
        float acc = bkq[h];
        for (int e = 0; e < EE; e++) acc += XsT[e * TXS + s] * wkq[e * NHH + h];
        acc *= 0.5f;
        if (s >= P.len) acc -= 1e9f;
        sc[h * SLEN + s] = acc;
    }
    __syncthreads();
    for (int h = wid; h < NHH; h += 4) {
        float v = sc[h * SLEN + lane];
        float mx = v;
        #pragma unroll
        for (int o = 32; o; o >>= 1) mx = fmaxf(mx, __shfl_xor(mx, o));
        float ex = __expf(v - mx);
        float sm = ex;
        #pragma unroll
        for (int o = 32; o; o >>= 1) sm += __shfl_xor(sm, o);
        sc[h * SLEN + lane] = ex / sm;
    }
    __syncthreads();
    for (int t = tid; t < NHH * EE; t += 256) {
        int h = t / EE, e = t - h * EE;      // lanes vary e: XsT stride-65 (odd) reads
        float acc = 0.f;
        for (int s = 0; s < SLEN; s++) acc += sc[h * SLEN + s] * XsT[e * TXS + s];
        su[t] = acc;
    }
    __syncthreads();
    if (tid < 32) {
        float acc = ldf<BF16>(bv, tid);
        int h = tid >> 2;
        for (int e = 0; e < EE; e++) acc += su[h * EE + e] * ldf<BF16>(wvv, e * 32 + tid);
        sctx[tid] = acc;
    }
    __syncthreads();
    if (tid < EE) {
        float acc = ldf<BF16>(bo, tid);
        #pragma unroll
        for (int i = 0; i < 32; i++) acc += sctx[i] * ldf<BF16>(wo, i * EE + tid);
        P.feat[176 + tid] = acc;
    }
    __syncthreads();

    // ---------------- phase 4: MLP ----------------
    float z1 = 0.f;
    if (tid < H1D) {
        z1 = ldf<BF16>(b1, tid);
        for (int i = 0; i < INDIM; i++) z1 += P.feat[i] * ldf<BF16>(w1, i * H1D + tid);
        P.buf[tid] = z1;
    }
    __syncthreads();
    if (tid < 64) {
        float sm = 0.f, sq = 0.f;
        for (int j = tid; j < H1D; j += 64) { float v = P.buf[j]; sm += v; sq += v * v; }
        #pragma unroll
        for (int o = 32; o; o >>= 1) { sm += __shfl_xor(sm, o); sq += __shfl_xor(sq, o); }
        if (tid == 0) { float mu = sm / H1D; P.mu = mu; P.rstd = rsqrtf(sq / H1D - mu * mu + 1e-3f); }
    }
    __syncthreads();
    if (tid < H1D) {
        float h = fmaxf(ldf<BF16>(g1, tid) * (z1 - P.mu) * P.rstd + ldf<BF16>(be1, tid), 0.f);
        P.buf[256 + tid] = h;
    }
    __syncthreads();
    float z2 = 0.f;
    if (tid < H2D) {
        z2 = ldf<BF16>(b2, tid);
        for (int i = 0; i < H1D; i++) z2 += P.buf[256 + i] * ldf<BF16>(w2, i * H2D + tid);
        P.buf[tid] = z2;
    }
    __syncthreads();
    if (tid < 64) {
        float sm = 0.f, sq = 0.f;
        for (int j = tid; j < H2D; j += 64) { float v = P.buf[j]; sm += v; sq += v * v; }
        #pragma unroll
        for (int o = 32; o; o >>= 1) { sm += __shfl_xor(sm, o); sq += __shfl_xor(sq, o); }
        if (tid == 0) { float mu = sm / H2D; P.mu = mu; P.rstd = rsqrtf(sq / H2D - mu * mu + 1e-3f); }
    }
    __syncthreads();
    if (tid < H2D) {
        float h = fmaxf(ldf<BF16>(g2, tid) * (z2 - P.mu) * P.rstd + ldf<BF16>(be2, tid), 0.f);
        P.red[tid] = h * ldf<BF16>(w3, tid);
    }
    __syncthreads();
    if (tid == 0) {
        float acc = ldf<BF16>(b3, 0);
        for (int i = 0; i < H2D; i++) acc += P.red[i];
        float sig = 1.f / (1.f + __expf(-acc));
        if constexpr (BF16) ((__hip_bfloat16*)outp)[b] = __float2bfloat16(sig);
        else                ((float*)outp)[b] = sig;
    }
}

__global__ __launch_bounds__(256, 2) void sdim_fwd(
    const int* __restrict__ uid, const int* __restrict__ ut1, const int* __restrict__ ut2,
    const int* __restrict__ ut3, const int* __restrict__ ut4,
    const int* __restrict__ lb_g, const int* __restrict__ lb_s, const int* __restrict__ lb_c,
    const int* __restrict__ lt_g, const int* __restrict__ lt_s, const int* __restrict__ lt_c,
    const int* __restrict__ st_g, const int* __restrict__ st_s, const int* __restrict__ st_c,
    const void* __restrict__ tbl, const void* __restrict__ Hm,
    const void* __restrict__ wq, const void* __restrict__ bq,
    const void* __restrict__ wk, const void* __restrict__ bk,
    const void* __restrict__ wvv, const void* __restrict__ bv,
    const void* __restrict__ wo, const void* __restrict__ bo,
    const void* __restrict__ w1, const void* __restrict__ b1,
    const void* __restrict__ g1, const void* __restrict__ be1,
    const void* __restrict__ w2, const void* __restrict__ b2,
    const void* __restrict__ g2, const void* __restrict__ be2,
    const void* __restrict__ w3, const void* __restrict__ b3,
    void* __restrict__ outp)
{
    __shared__ Pool P;
    __shared__ int s_isbf;
    // dtype detect: bf16 evens are small values (exp<127); fp32 evens are random
    // mantissa bits (P[all 128 exp<127] ~ 2^-128).
    if (threadIdx.x < 64) {
        int big = 0;
        for (int i = (threadIdx.x & 63); i < 128; i += 64) {
            unsigned short u = ((const unsigned short*)tbl)[2 * i];
            if (((u >> 7) & 0xFF) >= 127) big = 1;
        }
        unsigned long long m = __ballot(big);
        if (threadIdx.x == 0) s_isbf = (m == 0ull) ? 1 : 0;
    }
    __syncthreads();
    if (s_isbf)
        sdim_body<true >(P, uid, ut1, ut2, ut3, ut4, lb_g, lb_s, lb_c, lt_g, lt_s, lt_c,
                         st_g, st_s, st_c, tbl, Hm, wq, bq, wk, bk, wvv, bv, wo, bo,
                         w1, b1, g1, be1, w2, b2, g2, be2, w3, b3, outp);
    else
        sdim_body<false>(P, uid, ut1, ut2, ut3, ut4, lb_g, lb_s, lb_c, lt_g, lt_s, lt_c,
                         st_g, st_s, st_c, tbl, Hm, wq, bq, wk, bk, wvv, bv, wo, bo,
                         w1, b1, g1, be1, w2, b2, g2, be2, w3, b3, outp);
}

extern "C" void kernel_launch(void* const* d_in, const int* in_sizes, int n_in,
                              void* d_out, int out_size, void* d_ws, size_t ws_size,
                              hipStream_t stream) {
    const int B = in_sizes[0];   // batch = 1024
    sdim_fwd<<<B, 256, 0, stream>>>(
        (const int*)d_in[0],  (const int*)d_in[1],  (const int*)d_in[2],
        (const int*)d_in[3],  (const int*)d_in[4],
        (const int*)d_in[5],  (const int*)d_in[6],  (const int*)d_in[7],
        (const int*)d_in[8],  (const int*)d_in[9],  (const int*)d_in[10],
        (const int*)d_in[11], (const int*)d_in[12], (const int*)d_in[13],
        (const void*)d_in[14], (const void*)d_in[15],
        (const void*)d_in[16], (const void*)d_in[17],
        (const void*)d_in[18], (const void*)d_in[19],
        (const void*)d_in[20], (const void*)d_in[21],
        (const void*)d_in[22], (const void*)d_in[23],
        (const void*)d_in[24], (const void*)d_in[25],
        (const void*)d_in[26], (const void*)d_in[27],
        (const void*)d_in[28], (const void*)d_in[29],
        (const void*)d_in[30], (const void*)d_in[31],
        (const void*)d_in[32], (const void*)d_in[33],
        d_out);
}